// Round 14
// baseline (35.678 us; speedup 1.0000x reference)
//
#include <hip/hip_runtime.h>

static constexpr int kNodes  = 100000;
static constexpr int kEdges  = 1600000;
static constexpr int kPairs  = kEdges / 2;
static constexpr int kD      = 128;
static constexpr int kNPG    = 8;                  // nodes per 16-lane group
static constexpr int kGroups = kNodes / kNPG;      // 12500

typedef float              fx4 __attribute__((ext_vector_type(4)));
typedef unsigned long long u64;
typedef u64                ux2 __attribute__((ext_vector_type(2)));

// ---------------------------------------------------------------------------
// Phase 1: per-node difference dots, 8 consecutive nodes per 16-lane group.
//   u[n] = emb[n]·(W1-W0)[0:128], v[n] = emb[n]·(W1-W0)[128:256]
// 16 fx4 loads issued back-to-back (16KB/wave in flight vs 8KB in R13 —
// deeper MLP against cold-HBM latency); W regs amortized over 8 nodes;
// lane0 accumulates 4 fx4 of packed (u,v) pairs, 64B store per group.
// ---------------------------------------------------------------------------
__global__ __launch_bounds__(256) void node_pre(const float* __restrict__ emb,
                                                const float* __restrict__ W,
                                                float* __restrict__ uv) {
    const int l  = threadIdx.x & 15;   // lane within 16-group
    const int c0 = l * 8;

    fx4 w0a = *(const fx4*)&W[c0],       w0b = *(const fx4*)&W[c0 + 4];
    fx4 w1a = *(const fx4*)&W[256 + c0], w1b = *(const fx4*)&W[256 + c0 + 4];
    fx4 dua = w1a - w0a, dub = w1b - w0b;
    fx4 w2a = *(const fx4*)&W[128 + c0], w2b = *(const fx4*)&W[128 + c0 + 4];
    fx4 w3a = *(const fx4*)&W[384 + c0], w3b = *(const fx4*)&W[384 + c0 + 4];
    fx4 dva = w3a - w2a, dvb = w3b - w2b;

    const int g = (blockIdx.x * blockDim.x + threadIdx.x) >> 4;
    if (g >= kGroups) return;
    const int n0 = g * kNPG;

    // 16 independent fx4 loads, all issued before any use
    fx4 ea[kNPG], eb[kNPG];
    {
        const float* base = emb + (size_t)n0 * kD + c0;
#pragma unroll
        for (int j = 0; j < kNPG; ++j) {
            ea[j] = *(const fx4*)(base + j * kD);
            eb[j] = *(const fx4*)(base + j * kD + 4);
        }
    }

    fx4 pk[kNPG / 2];   // lane0: {u,v} pairs for nodes j, j+1

#pragma unroll
    for (int j = 0; j < kNPG; ++j) {
        float pu = ea[j].x*dua.x + ea[j].y*dua.y + ea[j].z*dua.z + ea[j].w*dua.w
                 + eb[j].x*dub.x + eb[j].y*dub.y + eb[j].z*dub.z + eb[j].w*dub.w;
        float pv = ea[j].x*dva.x + ea[j].y*dva.y + ea[j].z*dva.z + ea[j].w*dva.w
                 + eb[j].x*dvb.x + eb[j].y*dvb.y + eb[j].z*dvb.z + eb[j].w*dvb.w;
        float keep = (l & 1) ? pv : pu;
        float send = (l & 1) ? pu : pv;
        float x = keep + __shfl_xor(send, 1);
        x += __shfl_xor(x, 2);
        x += __shfl_xor(x, 4);
        x += __shfl_xor(x, 8);
        float other = __shfl_xor(x, 1);   // lane0: v_j
        if ((j & 1) == 0) { pk[j / 2].x = x; pk[j / 2].y = other; }
        else              { pk[j / 2].z = x; pk[j / 2].w = other; }
    }

    if (l == 0) {
#pragma unroll
        for (int j = 0; j < kNPG / 2; ++j)
            ((fx4*)uv)[g * (kNPG / 2) + j] = pk[j];
    }
}

// ---------------------------------------------------------------------------
// Phase 2: R7 edge kernel with 16B index loads (2 instead of 4 per thread).
// Measured ~15 us ≈ random-gather machinery limit (3.2M 4B lane-gathers;
// invariant to L1-bypass and batching per R11). d = u[r]+v[c]+db.
// ---------------------------------------------------------------------------
__global__ __launch_bounds__(256) void edge_attn(const void* __restrict__ eiv,
                                                 const float* __restrict__ uv,
                                                 const float* __restrict__ b,
                                                 float* __restrict__ out) {
    const u64* ei64 = (const u64*)eiv;
    u64 hi = ei64[threadIdx.x & 63] >> 32;
    const bool is64 = (__ballot(hi != 0ull) == 0ull);

    const int e2 = blockIdx.x * blockDim.x + threadIdx.x;   // pair index
    if (e2 >= kPairs) return;

    int r0, r1, c0i, c1i;
    if (is64) {
        ux2 rr = ((const ux2*)ei64)[e2];
        ux2 cc = ((const ux2*)(ei64 + kEdges))[e2];
        r0  = (int)rr.x; r1  = (int)rr.y;
        c0i = (int)cc.x; c1i = (int)cc.y;
    } else {
        const int* ei32 = (const int*)eiv;
        r0  = ei32[2 * e2];          r1  = ei32[2 * e2 + 1];
        c0i = ei32[kEdges + 2 * e2]; c1i = ei32[kEdges + 2 * e2 + 1];
    }

    const float db = b[1] - b[0];

    float d0 = uv[2 * r0] + uv[2 * c0i + 1] + db;
    float d1 = uv[2 * r1] + uv[2 * c1i + 1] + db;

    float p00 = __builtin_amdgcn_rcpf(1.0f + __expf(d0));
    float p10 = __builtin_amdgcn_rcpf(1.0f + __expf(d1));

    fx4 o = {p00, 1.0f - p00, p10, 1.0f - p10};
    ((fx4*)out)[e2] = o;
}

extern "C" void kernel_launch(void* const* d_in, const int* in_sizes, int n_in,
                              void* d_out, int out_size, void* d_ws, size_t ws_size,
                              hipStream_t stream) {
    const float* emb = (const float*)d_in[0];
    const void*  ei  = d_in[1];
    const float* W   = (const float*)d_in[2];
    const float* b   = (const float*)d_in[3];
    float* out = (float*)d_out;

    float* uv = (float*)d_ws;   // 800 KB node table

    node_pre<<<(kGroups * 16 + 255) / 256, 256, 0, stream>>>(emb, W, uv);
    edge_attn<<<(kPairs + 255) / 256, 256, 0, stream>>>(ei, uv, b, out);
}

// Round 15
// 31.442 us; speedup vs baseline: 1.1348x; 1.1348x over previous
//
#include <hip/hip_runtime.h>

static constexpr int kNodes  = 100000;
static constexpr int kEdges  = 1600000;
static constexpr int kPairs  = kEdges / 2;
static constexpr int kD      = 128;
static constexpr int kGroups = kNodes / 4;   // 25000 groups of 4 consecutive nodes

typedef float              fx4 __attribute__((ext_vector_type(4)));
typedef unsigned long long u64;

// ---------------------------------------------------------------------------
// R13 kernels, byte-identical (best measured: 31.35 us).
// Phase 1: per-node difference dots, 4 consecutive nodes per 16-lane group.
//   u[n] = emb[n]·(W1-W0)[0:128], v[n] = emb[n]·(W1-W0)[128:256]
// 8 fx4 loads in flight; W regs amortized over 4 nodes; lane0 packs (u,v)
// for all 4 nodes, two fx4 stores. 4-node is the ILP/occupancy sweet spot:
// 8-node (R14) regressed via VGPR pressure; 1-node (R7) lacked MLP.
// ---------------------------------------------------------------------------
__global__ __launch_bounds__(256) void node_pre(const float* __restrict__ emb,
                                                const float* __restrict__ W,
                                                float* __restrict__ uv) {
    const int l  = threadIdx.x & 15;   // lane within 16-group
    const int c0 = l * 8;

    fx4 w0a = *(const fx4*)&W[c0],       w0b = *(const fx4*)&W[c0 + 4];
    fx4 w1a = *(const fx4*)&W[256 + c0], w1b = *(const fx4*)&W[256 + c0 + 4];
    fx4 dua = w1a - w0a, dub = w1b - w0b;
    fx4 w2a = *(const fx4*)&W[128 + c0], w2b = *(const fx4*)&W[128 + c0 + 4];
    fx4 w3a = *(const fx4*)&W[384 + c0], w3b = *(const fx4*)&W[384 + c0 + 4];
    fx4 dva = w3a - w2a, dvb = w3b - w2b;

    const int g = (blockIdx.x * blockDim.x + threadIdx.x) >> 4;
    if (g >= kGroups) return;
    const int n0 = g * 4;

    // batched loads: 8 independent fx4 loads in flight
    fx4 ea0, eb0, ea1, eb1, ea2, eb2, ea3, eb3;
    {
        const float* base = emb + (size_t)n0 * kD + c0;
        ea0 = *(const fx4*)(base);
        eb0 = *(const fx4*)(base + 4);
        ea1 = *(const fx4*)(base + kD);
        eb1 = *(const fx4*)(base + kD + 4);
        ea2 = *(const fx4*)(base + 2 * kD);
        eb2 = *(const fx4*)(base + 2 * kD + 4);
        ea3 = *(const fx4*)(base + 3 * kD);
        eb3 = *(const fx4*)(base + 3 * kD + 4);
    }

    fx4 pair01, pair23;   // lane0: {u0,v0,u1,v1}, {u2,v2,u3,v3}

#define DO_NODE(EA, EB, SLOT0, SLOT1, PAIR)                                   \
    {                                                                         \
        float pu = EA.x*dua.x + EA.y*dua.y + EA.z*dua.z + EA.w*dua.w          \
                 + EB.x*dub.x + EB.y*dub.y + EB.z*dub.z + EB.w*dub.w;         \
        float pv = EA.x*dva.x + EA.y*dva.y + EA.z*dva.z + EA.w*dva.w          \
                 + EB.x*dvb.x + EB.y*dvb.y + EB.z*dvb.z + EB.w*dvb.w;         \
        float keep = (l & 1) ? pv : pu;                                       \
        float send = (l & 1) ? pu : pv;                                       \
        float x = keep + __shfl_xor(send, 1);                                 \
        x += __shfl_xor(x, 2);                                                \
        x += __shfl_xor(x, 4);                                                \
        x += __shfl_xor(x, 8);                                                \
        float other = __shfl_xor(x, 1);  /* lane0: v_j */                     \
        PAIR.SLOT0 = x;                                                       \
        PAIR.SLOT1 = other;                                                   \
    }

    DO_NODE(ea0, eb0, x, y, pair01)
    DO_NODE(ea1, eb1, z, w, pair01)
    DO_NODE(ea2, eb2, x, y, pair23)
    DO_NODE(ea3, eb3, z, w, pair23)
#undef DO_NODE

    if (l == 0) {
        ((fx4*)uv)[g * 2]     = pair01;   // uv[8g .. 8g+4)
        ((fx4*)uv)[g * 2 + 1] = pair23;   // uv[8g+4 .. 8g+8)
    }
}

// ---------------------------------------------------------------------------
// Phase 2: R7 edge kernel (measured ~15 us; invariant to L1-bypass, batching,
// split tables, wider index loads -> pinned by random-gather machinery +
// 38.4 MB stream). 2 edges/thread; d = u[r]+v[c]+db; p = 1/(1+e^d).
// ---------------------------------------------------------------------------
__global__ __launch_bounds__(256) void edge_attn(const void* __restrict__ eiv,
                                                 const float* __restrict__ uv,
                                                 const float* __restrict__ b,
                                                 float* __restrict__ out) {
    const u64* ei64 = (const u64*)eiv;
    u64 hi = ei64[threadIdx.x & 63] >> 32;
    const bool is64 = (__ballot(hi != 0ull) == 0ull);

    const int e2 = blockIdx.x * blockDim.x + threadIdx.x;   // pair index
    if (e2 >= kPairs) return;

    int r0, r1, c0i, c1i;
    if (is64) {
        const u64* rr = ei64 + 2 * e2;
        const u64* cc = ei64 + kEdges + 2 * e2;
        r0  = (int)rr[0]; r1  = (int)rr[1];
        c0i = (int)cc[0]; c1i = (int)cc[1];
    } else {
        const int* ei32 = (const int*)eiv;
        r0  = ei32[2 * e2];          r1  = ei32[2 * e2 + 1];
        c0i = ei32[kEdges + 2 * e2]; c1i = ei32[kEdges + 2 * e2 + 1];
    }

    const float db = b[1] - b[0];

    float d0 = uv[2 * r0] + uv[2 * c0i + 1] + db;
    float d1 = uv[2 * r1] + uv[2 * c1i + 1] + db;

    float p00 = __builtin_amdgcn_rcpf(1.0f + __expf(d0));
    float p10 = __builtin_amdgcn_rcpf(1.0f + __expf(d1));

    fx4 o = {p00, 1.0f - p00, p10, 1.0f - p10};
    ((fx4*)out)[e2] = o;
}

extern "C" void kernel_launch(void* const* d_in, const int* in_sizes, int n_in,
                              void* d_out, int out_size, void* d_ws, size_t ws_size,
                              hipStream_t stream) {
    const float* emb = (const float*)d_in[0];
    const void*  ei  = d_in[1];
    const float* W   = (const float*)d_in[2];
    const float* b   = (const float*)d_in[3];
    float* out = (float*)d_out;

    float* uv = (float*)d_ws;   // 800 KB node table

    node_pre<<<(kGroups * 16 + 255) / 256, 256, 0, stream>>>(emb, W, uv);
    edge_attn<<<(kPairs + 255) / 256, 256, 0, stream>>>(ei, uv, b, out);
}